// Round 8
// baseline (175.527 us; speedup 1.0000x reference)
//
#include <hip/hip_runtime.h>
#include <stdint.h>
#include <math.h>

// ---------------------------------------------------------------------------
// IID segmentation loss on MI355X.  Round 10.
// R9 refuted LDS-volume theory: ops 530->376/row, conflicts -31%, clean regs
// -> corr 57.4->61us. All variants (R2/R4/R9) land 56-62us across wildly
// different LDS/conflict/occupancy configs -> binder is the single 640-thr
// barrier domain (1 block/CU): ~35-40K cyc/CU of barrier+serial-chain stall.
// R10: TWO barrier domains per CU. N-split: block = 10M x 5N classes (50
// tiles), 5 waves of R4's proven 2Mx5N acc[2][5], grid 512. ldsB 37.1KB +
// single-buffer 8-plane ldsA 38.5KB = 75.6KB -> 2 blocks/CU. 2 barriers/row
// (R2's proven single-buffer pattern). Paired N-halves share A via L2
// (swizzle keeps them on one XCD). Tail = R7 verbatim.
// ---------------------------------------------------------------------------

#define PADV 7
#define TS 15
#define KCLS 10
#define HH 224
#define WW 224
#define MD 160
#define NCELL (MD*MD)
#define NGRID 256            // partial grids (one per (batch, y-group))
#define TY 14
#define BSTRIDE 232
#define BPH 240
#define PLANEE 2408          // elems per shift-plane (10*240 + 8 pad)
#define ABUFE (8*PLANEE)     // elems per A buffer (8 planes, single-buffered)
#define NRED 400             // reduce_all blocks (=mins entries)
#define LEPS 1e-16

typedef __attribute__((ext_vector_type(4))) float f32x4;
typedef __attribute__((ext_vector_type(8))) short bf16x8;

__device__ __forceinline__ unsigned short f2bf(float f) {
  union { float f; uint32_t u; } v; v.f = f;
  return (unsigned short)((v.u + 0x7FFFu + ((v.u >> 16) & 1u)) >> 16);
}

__device__ __forceinline__ uint32_t pack2bf(float a, float b) {
  return (uint32_t)f2bf(a) | ((uint32_t)f2bf(b) << 16);
}

__device__ __forceinline__ void glds16(const unsigned short* g, unsigned short* l) {
  __builtin_amdgcn_global_load_lds(
      (const __attribute__((address_space(1))) unsigned int*)g,
      (__attribute__((address_space(3))) unsigned int*)l, 16, 0, 0);
}

// Write the 8 shift-planes for one (class, 8-elem chunk) from 16 loaded f32.
__device__ __forceinline__ void plane_write(const f32x4 f[4], unsigned short* awr) {
  uint32_t w[8];
#pragma unroll
  for (int k = 0; k < 8; ++k)
    w[k] = pack2bf(f[k >> 1][(k & 1) * 2], f[k >> 1][(k & 1) * 2 + 1]);
#pragma unroll
  for (int c = 0; c < 8; ++c) {
    union { uint32_t u[4]; uint4 v; } o;
    if (c & 1) {
#pragma unroll
      for (int j = 0; j < 4; ++j) o.u[j] = w[j + (c + 1) / 2];
    } else {
#pragma unroll
      for (int j = 0; j < 4; ++j)
        o.u[j] = __builtin_amdgcn_alignbit(w[j + 1 + c / 2], w[j + c / 2], 16);
    }
    *(uint4*)(awr + c * PLANEE) = o.v;
  }
}

// Bpad[cls][yy][x]: cls=b*10+o, yy in [0,240) <-> row=yy-7, x in [0,232).
__global__ __launch_bounds__(256)
void prep_b(const float* __restrict__ xt, unsigned short* __restrict__ bp) {
  const int idx   = blockIdx.x * 256 + threadIdx.x;
  const int rowid = idx / 29;
  const int chunk = idx - rowid * 29;
  const int x0    = chunk * 8;
  const int yy    = rowid % BPH;
  const int cls   = rowid / BPH;
  const int row   = yy - PADV;
  union { unsigned short h[8]; uint4 v; } out;
  if (row >= 0 && row < HH && chunk < 28) {
    const float4* src = (const float4*)(xt + ((size_t)cls * HH + row) * WW + x0);
    const float4 f0 = src[0], f1 = src[1];
    out.h[0] = f2bf(f0.x); out.h[1] = f2bf(f0.y);
    out.h[2] = f2bf(f0.z); out.h[3] = f2bf(f0.w);
    out.h[4] = f2bf(f1.x); out.h[5] = f2bf(f1.y);
    out.h[6] = f2bf(f1.z); out.h[7] = f2bf(f1.w);
  } else {
    out.v = make_uint4(0u, 0u, 0u, 0u);
  }
  *(uint4*)(bp + (size_t)rowid * BSTRIDE + x0) = out.v;
}

#define MFMA_BF16 __builtin_amdgcn_mfma_f32_16x16x32_bf16

// 320 threads = 5 waves. Block (b, yg, nh): all 10 M-classes x 5 N-classes
// [nh*5, nh*5+5). Wave wv owns M-pair {2wv, 2wv+1} x the 5 local N-tiles.
__global__ __launch_bounds__(320)
void corr_gemm(const float* __restrict__ xo, const unsigned short* __restrict__ bpad,
               float* __restrict__ partials) {
  __shared__ __align__(16) unsigned short ldsA8[ABUFE];           // 38528 B
  __shared__ __align__(16) unsigned short ldsB[5 * 16 * BSTRIDE]; // 37120 B

  const int tid  = threadIdx.x;
  const int bid0 = blockIdx.x;
  // XCD swizzle, 512 blocks: lb and lb+1 (the two N-halves of one (b,yg))
  // map to bid0 and bid0+8 -> same XCD -> shared A rows are L2-local.
  const int lb   = (bid0 & 7) * 64 + (bid0 >> 3);
  const int b    = lb >> 5;            // 16 batches
  const int yg   = (lb >> 1) & 15;     // 16 y-groups
  const int nh   = lb & 1;             // N-half
  const int y0   = yg * TY;

  const int lane = tid & 63;
  const int wv   = tid >> 6;           // 0..4
  const int quad = lane >> 4;
  const int l15  = lane & 15;
  const int q8   = quad * 8;

  f32x4 acc[2][5];
#pragma unroll
  for (int i = 0; i < 2; ++i)
#pragma unroll
    for (int j = 0; j < 5; ++j) acc[i][j] = (f32x4){0.f, 0.f, 0.f, 0.f};

  const float* Ab = xo + (size_t)b * KCLS * HH * WW;
  const unsigned short* Bb = bpad + (size_t)b * KCLS * BPH * BSTRIDE;

  // A-row loader geometry: threads 0..299 -> (class an, chunk atp in [0,30)).
  const bool aw  = tid < 300;
  const int an   = aw ? tid / 30 : 0;
  const int atp  = aw ? tid - (tid / 30) * 30 : 0;
  const int axb  = atp * 8 - 8;        // global x of f[0].x
  bool gv[4];
#pragma unroll
  for (int g = 0; g < 4; ++g)
    gv[g] = aw && (axb + 4 * g >= 0) && (axb + 4 * g + 4 <= WW);
  unsigned short* const awr0 = ldsA8 + an * 240 + atp * 8;

  // prologue: async preload B rows y0-7..y0+7 for this block's 5 classes;
  // wave wv loads its own class (nh*5+wv) for all 15 rows.
  for (int r15 = 0; r15 < 15; ++r15) {
    const int yy   = y0 + r15;                 // row = y0-7+r15
    const int slot = (y0 - PADV + r15) & 15;
    if (lane < 29)
      glds16(Bb + ((size_t)(nh * 5 + wv) * BPH + yy) * BSTRIDE + lane * 8,
             ldsB + (wv * 16 + slot) * BSTRIDE);
  }

  // prologue: A row y0 -> planes
  f32x4 f[4];
  {
    const float* src = Ab + ((size_t)an * HH + y0) * WW + axb;
#pragma unroll
    for (int g = 0; g < 4; ++g) {
      f[g] = (f32x4){0.f, 0.f, 0.f, 0.f};
      if (gv[g]) f[g] = *(const f32x4*)(src + 4 * g);
    }
  }
  if (aw) plane_write(f, awr0);
  __syncthreads();  // drains B prologue DMA + publishes A planes

  for (int s = 0; s < TY; ++s) {
    const int y = y0 + s;
    const bool more = (s + 1 < TY);

    if (more) {
      // async DMA: B row y+8 into dead slot (one class-row per wave)
      const int yy   = y + 8 + PADV;
      const int slot = (y + 8) & 15;
      if (lane < 29)
        glds16(Bb + ((size_t)(nh * 5 + wv) * BPH + yy) * BSTRIDE + lane * 8,
               ldsB + (wv * 16 + slot) * BSTRIDE);
      // issue A row y+1 global loads early (latency hides under MFMAs)
      const float* src = Ab + ((size_t)an * HH + (y + 1)) * WW + axb;
#pragma unroll
      for (int g = 0; g < 4; ++g) {
        f[g] = (f32x4){0.f, 0.f, 0.f, 0.f};
        if (gv[g]) f[g] = *(const f32x4*)(src + 4 * g);
      }
    }

    // per-lane bases: A plane read is a single aligned b128, conflict-free
    const unsigned short* paB = ldsA8 + (l15 & 7) * PLANEE + (l15 & 8);
    const int slotB = (y + PADV - l15) & 15;

#pragma unroll 1
    for (int xc = 0; xc < 7; ++xc) {
      const int qo = xc * 32 + q8;
      bf16x8 afrag[2], bfrag[5];
#pragma unroll
      for (int mi = 0; mi < 2; ++mi)
        afrag[mi] = *(const bf16x8*)(paB + (2 * wv + mi) * 240 + qo);
#pragma unroll
      for (int ni = 0; ni < 5; ++ni)
        bfrag[ni] = *(const bf16x8*)(ldsB + (ni * 16 + slotB) * BSTRIDE + qo);
#pragma unroll
      for (int mi = 0; mi < 2; ++mi)
#pragma unroll
        for (int ni = 0; ni < 5; ++ni)
          acc[mi][ni] = MFMA_BF16(afrag[mi], bfrag[ni], acc[mi][ni], 0, 0, 0);
    }

    if (more) {
      __syncthreads();  // all reads of ldsA done; B DMA drained
      if (aw) plane_write(f, awr0);
      __syncthreads();  // A row y+1 published
    }
  }

  float* outp = partials + (size_t)(b * 16 + yg) * NCELL;
#pragma unroll
  for (int mi = 0; mi < 2; ++mi)
#pragma unroll
    for (int ni = 0; ni < 5; ++ni) {
      const int mrow = (2 * wv + mi) * 16 + quad * 4;
      const int ncol = (nh * 5 + ni) * 16 + l15;
#pragma unroll
      for (int r = 0; r < 4; ++r)
        outp[(size_t)(mrow + r) * MD + ncol] = acc[mi][ni][r];
    }
}

// Fused reduce: 400 blocks. Block covers 64 cells; thread (cl,g) sums grids
// [g*64,(g+1)*64) for cell c = bid*64+cl; LDS-combine 4 groups; per-block min.
__global__ __launch_bounds__(256)
void reduce_all(const float* __restrict__ partials, float* __restrict__ Cout,
                float* __restrict__ mins, float* __restrict__ dout) {
  const int tid = threadIdx.x;
  const int cl  = tid & 63;
  const int g   = tid >> 6;
  const int c   = blockIdx.x * 64 + cl;
  if (blockIdx.x == 0 && tid == 0) dout[0] = 0.f;

  const float* base = partials + (size_t)g * 64 * NCELL + c;
  double s0 = 0.0, s1 = 0.0, s2 = 0.0, s3 = 0.0;
  for (int p = 0; p < 64; p += 4) {
    s0 += (double)base[(size_t)(p + 0) * NCELL];
    s1 += (double)base[(size_t)(p + 1) * NCELL];
    s2 += (double)base[(size_t)(p + 2) * NCELL];
    s3 += (double)base[(size_t)(p + 3) * NCELL];
  }
  __shared__ double redd[256];
  redd[tid] = (s0 + s1) + (s2 + s3);
  __syncthreads();

  __shared__ float redm[64];
  if (tid < 64) {
    const double tot = redd[tid] + redd[tid + 64] + redd[tid + 128] + redd[tid + 192];
    const float sf = (float)tot;
    Cout[c] = sf;
    const int m  = c / MD;
    const int nn = c - m * MD;
    const bool valid = ((m & 15) < TS) && ((nn & 15) < TS);
    redm[tid] = valid ? sf : 3.4e38f;
  }
  __syncthreads();
  for (int st = 32; st > 0; st >>= 1) {
    if (tid < st) redm[tid] = fminf(redm[tid], redm[tid + st]);
    __syncthreads();
  }
  if (tid == 0) mins[blockIdx.x] = redm[0];
}

__global__ __launch_bounds__(128)
void loss_kernel(const float* __restrict__ Cmat, const float* __restrict__ mins,
                 float* __restrict__ dout) {
  const int s   = blockIdx.x;
  const int dy  = s / TS;
  const int dx  = s - dy * TS;
  const int tid = threadIdx.x;
  __shared__ float fm[128];
  __shared__ double q[100];
  __shared__ double sym[100];
  __shared__ double pi[10], pj[10];
  __shared__ double red[128];

  {
    float v = 3.4e38f;
    for (int i = tid; i < NRED; i += 128) v = fminf(v, mins[i]);
    fm[tid] = v;
  }
  __syncthreads();
  for (int st = 64; st > 0; st >>= 1) {
    if (tid < st) fm[tid] = fminf(fm[tid], fm[tid + st]);
    __syncthreads();
  }
  const double minv = (double)fm[0];
  __syncthreads();

  if (tid < 100) {
    const int n = tid / 10, o = tid - (tid / 10) * 10;
    const double v = (double)Cmat[(size_t)(n * 16 + dx) * MD + (o * 16 + dy)];
    q[tid] = v - minv + LEPS;
  }
  __syncthreads();
  red[tid] = (tid < 100) ? q[tid] : 0.0;
  __syncthreads();
  for (int st = 64; st > 0; st >>= 1) {
    if (tid < st) red[tid] += red[tid + st];
    __syncthreads();
  }
  const double Z = red[0];
  __syncthreads();
  if (tid < 100) {
    const int n = tid / 10, o = tid - (tid / 10) * 10;
    sym[tid] = (q[n * 10 + o] + q[o * 10 + n]) * 0.5 / Z;
  }
  __syncthreads();
  if (tid < 10) {
    double a = 0.0, bsum = 0.0;
    for (int n2 = 0; n2 < 10; ++n2) {
      a    += sym[n2 * 10 + tid];
      bsum += sym[tid * 10 + n2];
    }
    pi[tid] = a;
    pj[tid] = bsum;
  }
  __syncthreads();
  double term = 0.0;
  if (tid < 100) {
    const int n = tid / 10, o = tid - (tid / 10) * 10;
    const double sp = sym[tid];
    term = -sp * (log(sp + LEPS) - log(pi[o] + LEPS) - log(pj[n] + LEPS));
  }
  red[tid] = term;
  __syncthreads();
  for (int st = 64; st > 0; st >>= 1) {
    if (tid < st) red[tid] += red[tid + st];
    __syncthreads();
  }
  if (tid == 0) atomicAdd(dout, (float)(red[0] / (double)(TS * TS)));
}

extern "C" void kernel_launch(void* const* d_in, const int* in_sizes, int n_in,
                              void* d_out, int out_size, void* d_ws, size_t ws_size,
                              hipStream_t stream) {
  const float* xo = (const float*)d_in[0];
  const float* xt = (const float*)d_in[1];
  float* ws       = (float*)d_ws;

  float* partials = ws;
  float* Cmat     = partials + (size_t)NGRID * NCELL;
  float* mins     = Cmat + NCELL;
  unsigned short* bpad = (unsigned short*)(mins + 512);
  float* out      = (float*)d_out;

  hipLaunchKernelGGL(prep_b,      dim3(4350), dim3(256), 0, stream, xt, bpad);
  hipLaunchKernelGGL(corr_gemm,   dim3(512),  dim3(320), 0, stream, xo, bpad, partials);
  hipLaunchKernelGGL(reduce_all,  dim3(NRED), dim3(256), 0, stream, partials, Cmat, mins, out);
  hipLaunchKernelGGL(loss_kernel, dim3(225),  dim3(128), 0, stream, Cmat, mins, out);
}

// Round 9
// 146.469 us; speedup vs baseline: 1.1984x; 1.1984x over previous
//
#include <hip/hip_runtime.h>
#include <stdint.h>
#include <math.h>

// ---------------------------------------------------------------------------
// IID segmentation loss on MI355X.  Round 11.
// R10 refuted the barrier-domain theory (2 domains/CU -> 84us; stage cost
// duplicated). R4 structure stays. This round fixes what the counter says:
// B-frag LDS reads at stride 232 elems = 116 dw == 20 (mod 32), gcd 4 ->
// 16 slot-rows on 8 bank-starts -> systematic 2-way conflict = 7.0M cyc
// (~2K cyc/row, 20% of row time). Fix: LDS B stride 236 elems (118 dw == 22
// mod 32, gcd 2 -> 16 distinct starts, provably minimal aliasing). Global
// bpad stays 232; DMA writes 464B into 472B rows (pad never read).
// Plus: #pragma unroll 2 on xc loop (pipeline reads under MFMAs) with
// launch_bounds(640,1) (cap 204, no spill risk; LDS still forces 1 blk/CU).
// Tail = R7 verbatim.
// ---------------------------------------------------------------------------

#define PADV 7
#define TS 15
#define KCLS 10
#define HH 224
#define WW 224
#define MD 160
#define NCELL (MD*MD)
#define NBLK 256
#define TY 14
#define BSTRIDE 232          // global bpad row stride (elems)
#define BSTRIDE_L 236        // LDS B row stride (elems): 118 dw == 22 mod 32
#define BPH 240
#define PLANEE 2408          // elems per shift-plane (10*240 + 8 pad)
#define ABUFE (8*PLANEE)     // elems per A buffer (8 planes)
#define NRED 400             // reduce_all blocks (=mins entries)
#define LEPS 1e-16

typedef __attribute__((ext_vector_type(4))) float f32x4;
typedef __attribute__((ext_vector_type(8))) short bf16x8;

__device__ __forceinline__ unsigned short f2bf(float f) {
  union { float f; uint32_t u; } v; v.f = f;
  return (unsigned short)((v.u + 0x7FFFu + ((v.u >> 16) & 1u)) >> 16);
}

__device__ __forceinline__ uint32_t pack2bf(float a, float b) {
  return (uint32_t)f2bf(a) | ((uint32_t)f2bf(b) << 16);
}

__device__ __forceinline__ void glds16(const unsigned short* g, unsigned short* l) {
  __builtin_amdgcn_global_load_lds(
      (const __attribute__((address_space(1))) unsigned int*)g,
      (__attribute__((address_space(3))) unsigned int*)l, 16, 0, 0);
}

// Write the 8 shift-planes for one (class, 8-elem chunk) from 16 loaded f32.
__device__ __forceinline__ void plane_write(const f32x4 f[4], unsigned short* awr) {
  uint32_t w[8];
#pragma unroll
  for (int k = 0; k < 8; ++k)
    w[k] = pack2bf(f[k >> 1][(k & 1) * 2], f[k >> 1][(k & 1) * 2 + 1]);
#pragma unroll
  for (int c = 0; c < 8; ++c) {
    union { uint32_t u[4]; uint4 v; } o;
    if (c & 1) {
#pragma unroll
      for (int j = 0; j < 4; ++j) o.u[j] = w[j + (c + 1) / 2];
    } else {
#pragma unroll
      for (int j = 0; j < 4; ++j)
        o.u[j] = __builtin_amdgcn_alignbit(w[j + 1 + c / 2], w[j + c / 2], 16);
    }
    *(uint4*)(awr + c * PLANEE) = o.v;
  }
}

// Bpad[cls][yy][x]: cls=b*10+o, yy in [0,240) <-> row=yy-7, x in [0,232).
__global__ __launch_bounds__(256)
void prep_b(const float* __restrict__ xt, unsigned short* __restrict__ bp) {
  const int idx   = blockIdx.x * 256 + threadIdx.x;
  const int rowid = idx / 29;
  const int chunk = idx - rowid * 29;
  const int x0    = chunk * 8;
  const int yy    = rowid % BPH;
  const int cls   = rowid / BPH;
  const int row   = yy - PADV;
  union { unsigned short h[8]; uint4 v; } out;
  if (row >= 0 && row < HH && chunk < 28) {
    const float4* src = (const float4*)(xt + ((size_t)cls * HH + row) * WW + x0);
    const float4 f0 = src[0], f1 = src[1];
    out.h[0] = f2bf(f0.x); out.h[1] = f2bf(f0.y);
    out.h[2] = f2bf(f0.z); out.h[3] = f2bf(f0.w);
    out.h[4] = f2bf(f1.x); out.h[5] = f2bf(f1.y);
    out.h[6] = f2bf(f1.z); out.h[7] = f2bf(f1.w);
  } else {
    out.v = make_uint4(0u, 0u, 0u, 0u);
  }
  *(uint4*)(bp + (size_t)rowid * BSTRIDE + x0) = out.v;
}

#define MFMA_BF16 __builtin_amdgcn_mfma_f32_16x16x32_bf16

__global__ __launch_bounds__(640, 1)
void corr_gemm(const float* __restrict__ xo, const unsigned short* __restrict__ bpad,
               float* __restrict__ partials) {
  __shared__ __align__(16) unsigned short ldsA8[2 * ABUFE];            // 77056 B
  __shared__ __align__(16) unsigned short ldsB[KCLS * 16 * BSTRIDE_L]; // 75520 B

  const int tid  = threadIdx.x;
  const int bid0 = blockIdx.x;
  // XCD-bijective swizzle (256 = 8*32): 32 consecutive logical blocks per XCD.
  const int bid  = (bid0 & 7) * 32 + (bid0 >> 3);
  const int b    = bid >> 4;           // 16 batches
  const int y0   = (bid & 15) * TY;    // 16 groups of 14 rows

  const int lane = tid & 63;
  const int wv   = tid >> 6;
  const int wm   = wv >> 1;
  const int wn   = wv & 1;
  const int quad = lane >> 4;
  const int l15  = lane & 15;

  f32x4 acc[2][5];
#pragma unroll
  for (int i = 0; i < 2; ++i)
#pragma unroll
    for (int j = 0; j < 5; ++j) acc[i][j] = (f32x4){0.f, 0.f, 0.f, 0.f};

  const float* Ab = xo + (size_t)b * KCLS * HH * WW;
  const unsigned short* Bb = bpad + (size_t)b * KCLS * BPH * BSTRIDE;

  // A-row loader geometry: threads 0..299 -> (class an, chunk atp in [0,30)).
  const bool aw  = tid < 300;
  const int an   = aw ? tid / 30 : 0;
  const int atp  = aw ? tid - (tid / 30) * 30 : 0;
  const int axb  = atp * 8 - 8;        // global x of f[0].x
  bool gv[4];
#pragma unroll
  for (int g = 0; g < 4; ++g)
    gv[g] = aw && (axb + 4 * g >= 0) && (axb + 4 * g + 4 <= WW);
  unsigned short* const awr0 = ldsA8 + an * 240 + atp * 8;

  // prologue: async preload B rows y0-7..y0+7 (150 class-rows, 15/wave)
  for (int pr = wv; pr < 15 * KCLS; pr += 10) {
    const int r15  = pr / KCLS;
    const int o    = pr - r15 * KCLS;
    const int yy   = y0 + r15;                 // row = y0-7+r15
    const int slot = (y0 - PADV + r15) & 15;
    if (lane < 29)
      glds16(Bb + ((size_t)o * BPH + yy) * BSTRIDE + lane * 8,
             ldsB + (o * 16 + slot) * BSTRIDE_L);
  }

  // prologue: A row y0 -> planes in buf 0
  f32x4 f[4];
  {
    const float* src = Ab + ((size_t)an * HH + y0) * WW + axb;
#pragma unroll
    for (int g = 0; g < 4; ++g) {
      f[g] = (f32x4){0.f, 0.f, 0.f, 0.f};
      if (gv[g]) f[g] = *(const f32x4*)(src + 4 * g);
    }
  }
  if (aw) plane_write(f, awr0);
  __syncthreads();  // drains B prologue DMA + publishes A planes (buf 0)

  int cur = 0;
  for (int s = 0; s < TY; ++s) {
    const int y = y0 + s;
    const bool more = (s + 1 < TY);

    if (more) {
      // async DMA: B row y+8 into dead slot (one class-row per wave)
      const int yy   = y + 8 + PADV;
      const int slot = (y + 8) & 15;
      if (lane < 29)
        glds16(Bb + ((size_t)wv * BPH + yy) * BSTRIDE + lane * 8,
               ldsB + (wv * 16 + slot) * BSTRIDE_L);
      // issue A row y+1 global loads early (latency hides under MFMAs)
      const float* src = Ab + ((size_t)an * HH + (y + 1)) * WW + axb;
#pragma unroll
      for (int g = 0; g < 4; ++g) {
        f[g] = (f32x4){0.f, 0.f, 0.f, 0.f};
        if (gv[g]) f[g] = *(const f32x4*)(src + 4 * g);
      }
    }

    // per-lane bases: A plane read is a single aligned b128, conflict-free
    const unsigned short* paB = ldsA8 + cur * ABUFE + (l15 & 7) * PLANEE + (l15 & 8);
    const int slotB = (y + PADV - l15) & 15;

#pragma unroll 2
    for (int xc = 0; xc < 7; ++xc) {
      const int x0 = xc * 32;
      bf16x8 afrag[2], bfrag[5];
#pragma unroll
      for (int mi = 0; mi < 2; ++mi)
        afrag[mi] = *(const bf16x8*)(paB + (wm * 2 + mi) * 240 + x0 + quad * 8);
#pragma unroll
      for (int ni = 0; ni < 5; ++ni) {
        const int to = wn * 5 + ni;
        bfrag[ni] = *(const bf16x8*)(ldsB + (to * 16 + slotB) * BSTRIDE_L + x0 + quad * 8);
      }
#pragma unroll
      for (int mi = 0; mi < 2; ++mi)
#pragma unroll
        for (int ni = 0; ni < 5; ++ni)
          acc[mi][ni] = MFMA_BF16(afrag[mi], bfrag[ni], acc[mi][ni], 0, 0, 0);
    }

    if (more) {
      if (aw) plane_write(f, awr0 + (cur ^ 1) * ABUFE);
      __syncthreads();  // drains B DMA + publishes A planes (buf cur^1)
      cur ^= 1;
    }
  }

  float* outp = partials + (size_t)bid * NCELL;
#pragma unroll
  for (int mi = 0; mi < 2; ++mi)
#pragma unroll
    for (int ni = 0; ni < 5; ++ni) {
      const int mrow = (wm * 2 + mi) * 16 + quad * 4;
      const int ncol = (wn * 5 + ni) * 16 + l15;
#pragma unroll
      for (int r = 0; r < 4; ++r)
        outp[(size_t)(mrow + r) * MD + ncol] = acc[mi][ni][r];
    }
}

// Fused reduce: 400 blocks. Block covers 64 cells; thread (cl,g) sums grids
// [g*64,(g+1)*64) for cell c = bid*64+cl; LDS-combine 4 groups; per-block min.
__global__ __launch_bounds__(256)
void reduce_all(const float* __restrict__ partials, float* __restrict__ Cout,
                float* __restrict__ mins, float* __restrict__ dout) {
  const int tid = threadIdx.x;
  const int cl  = tid & 63;
  const int g   = tid >> 6;
  const int c   = blockIdx.x * 64 + cl;
  if (blockIdx.x == 0 && tid == 0) dout[0] = 0.f;

  const float* base = partials + (size_t)g * 64 * NCELL + c;
  double s0 = 0.0, s1 = 0.0, s2 = 0.0, s3 = 0.0;
  for (int p = 0; p < 64; p += 4) {
    s0 += (double)base[(size_t)(p + 0) * NCELL];
    s1 += (double)base[(size_t)(p + 1) * NCELL];
    s2 += (double)base[(size_t)(p + 2) * NCELL];
    s3 += (double)base[(size_t)(p + 3) * NCELL];
  }
  __shared__ double redd[256];
  redd[tid] = (s0 + s1) + (s2 + s3);
  __syncthreads();

  __shared__ float redm[64];
  if (tid < 64) {
    const double tot = redd[tid] + redd[tid + 64] + redd[tid + 128] + redd[tid + 192];
    const float sf = (float)tot;
    Cout[c] = sf;
    const int m  = c / MD;
    const int nn = c - m * MD;
    const bool valid = ((m & 15) < TS) && ((nn & 15) < TS);
    redm[tid] = valid ? sf : 3.4e38f;
  }
  __syncthreads();
  for (int st = 32; st > 0; st >>= 1) {
    if (tid < st) redm[tid] = fminf(redm[tid], redm[tid + st]);
    __syncthreads();
  }
  if (tid == 0) mins[blockIdx.x] = redm[0];
}

__global__ __launch_bounds__(128)
void loss_kernel(const float* __restrict__ Cmat, const float* __restrict__ mins,
                 float* __restrict__ dout) {
  const int s   = blockIdx.x;
  const int dy  = s / TS;
  const int dx  = s - dy * TS;
  const int tid = threadIdx.x;
  __shared__ float fm[128];
  __shared__ double q[100];
  __shared__ double sym[100];
  __shared__ double pi[10], pj[10];
  __shared__ double red[128];

  {
    float v = 3.4e38f;
    for (int i = tid; i < NRED; i += 128) v = fminf(v, mins[i]);
    fm[tid] = v;
  }
  __syncthreads();
  for (int st = 64; st > 0; st >>= 1) {
    if (tid < st) fm[tid] = fminf(fm[tid], fm[tid + st]);
    __syncthreads();
  }
  const double minv = (double)fm[0];
  __syncthreads();

  if (tid < 100) {
    const int n = tid / 10, o = tid - (tid / 10) * 10;
    const double v = (double)Cmat[(size_t)(n * 16 + dx) * MD + (o * 16 + dy)];
    q[tid] = v - minv + LEPS;
  }
  __syncthreads();
  red[tid] = (tid < 100) ? q[tid] : 0.0;
  __syncthreads();
  for (int st = 64; st > 0; st >>= 1) {
    if (tid < st) red[tid] += red[tid + st];
    __syncthreads();
  }
  const double Z = red[0];
  __syncthreads();
  if (tid < 100) {
    const int n = tid / 10, o = tid - (tid / 10) * 10;
    sym[tid] = (q[n * 10 + o] + q[o * 10 + n]) * 0.5 / Z;
  }
  __syncthreads();
  if (tid < 10) {
    double a = 0.0, bsum = 0.0;
    for (int n2 = 0; n2 < 10; ++n2) {
      a    += sym[n2 * 10 + tid];
      bsum += sym[tid * 10 + n2];
    }
    pi[tid] = a;
    pj[tid] = bsum;
  }
  __syncthreads();
  double term = 0.0;
  if (tid < 100) {
    const int n = tid / 10, o = tid - (tid / 10) * 10;
    const double sp = sym[tid];
    term = -sp * (log(sp + LEPS) - log(pi[o] + LEPS) - log(pj[n] + LEPS));
  }
  red[tid] = term;
  __syncthreads();
  for (int st = 64; st > 0; st >>= 1) {
    if (tid < st) red[tid] += red[tid + st];
    __syncthreads();
  }
  if (tid == 0) atomicAdd(dout, (float)(red[0] / (double)(TS * TS)));
}

extern "C" void kernel_launch(void* const* d_in, const int* in_sizes, int n_in,
                              void* d_out, int out_size, void* d_ws, size_t ws_size,
                              hipStream_t stream) {
  const float* xo = (const float*)d_in[0];
  const float* xt = (const float*)d_in[1];
  float* ws       = (float*)d_ws;

  float* partials = ws;
  float* Cmat     = partials + (size_t)NBLK * NCELL;
  float* mins     = Cmat + NCELL;
  unsigned short* bpad = (unsigned short*)(mins + 512);
  float* out      = (float*)d_out;

  hipLaunchKernelGGL(prep_b,      dim3(4350), dim3(256), 0, stream, xt, bpad);
  hipLaunchKernelGGL(corr_gemm,   dim3(NBLK), dim3(640), 0, stream, xo, bpad, partials);
  hipLaunchKernelGGL(reduce_all,  dim3(NRED), dim3(256), 0, stream, partials, Cmat, mins, out);
  hipLaunchKernelGGL(loss_kernel, dim3(225),  dim3(128), 0, stream, Cmat, mins, out);
}